// Round 2
// baseline (93.244 us; speedup 1.0000x reference)
//
#include <hip/hip_runtime.h>
#include <hip/hip_bf16.h>

// Problem constants
#define B_    64
#define C_    1280
#define HW_   49
#define A_    40
#define BN    128          // d-tile per block (4 waves x 32 cols)
#define NK    (C_/32)      // 40 k-steps of 32
#define NTILE (C_/BN)      // 10

typedef short bf16x8 __attribute__((ext_vector_type(8)));
typedef float f32x4  __attribute__((ext_vector_type(4)));

__device__ __forceinline__ float hswish(float x) {
    float t = fminf(fmaxf(x + 3.0f, 0.0f), 6.0f);
    return x * t * (1.0f / 6.0f);
}

__device__ __forceinline__ short f2bf(float f) {
    __hip_bfloat16 h = __float2bfloat16(f);
    return __builtin_bit_cast(short, h);
}

// Kernel 1: avg pool (7x7) + h_swish + cvt to bf16. 64 rows per block,
// fully coalesced float4 staging into LDS, then per-row serial reduce.
#define POOL_ROWS 64
__global__ __launch_bounds__(256) void pool_kernel(const float* __restrict__ x,
                                                   __hip_bfloat16* __restrict__ p) {
    __shared__ float buf[POOL_ROWS * HW_];   // 3136 floats
    const int tid = threadIdx.x;
    const size_t base = (size_t)blockIdx.x * (POOL_ROWS * HW_);
    const float4* src = reinterpret_cast<const float4*>(x + base);  // 12544B-aligned
    #pragma unroll
    for (int i = 0; i < 3; ++i) {
        float4 v = src[tid + i * 256];
        *reinterpret_cast<float4*>(&buf[(tid + i * 256) * 4]) = v;
    }
    if (tid < 16) {
        float4 v = src[768 + tid];
        *reinterpret_cast<float4*>(&buf[(768 + tid) * 4]) = v;
    }
    __syncthreads();
    if (tid < POOL_ROWS) {
        float s = 0.f;
        #pragma unroll
        for (int j = 0; j < HW_; ++j) s += buf[tid * HW_ + j];
        s *= (1.0f / 49.0f);
        p[blockIdx.x * POOL_ROWS + tid] = __float2bfloat16(hswish(s));
    }
}

// Kernel 2: barrier-free head GEMM. Block = 4 waves; wave w owns cols
// [ntile*128 + w*32, +32) for ALL 64 batch rows. B-fragments load directly
// global->reg in MFMA layout (no LDS, no transpose, no sharing between waves).
// Depth-2 rotating prefetch, statically indexed via full unroll.
__global__ __launch_bounds__(256, 4) void head_kernel(
    const short* __restrict__ p,     // [64][1280] bf16
    const float* __restrict__ W1,    // [40][1280][1280]  ([a][k][d])
    const float* __restrict__ b1,    // [40][1280]
    const float* __restrict__ W2,    // [40][1280]
    float* __restrict__ part)        // [NTILE][64][40]
{
    __shared__ float red[4][B_];     // cross-wave reduce (epilogue only)

    const int tid  = threadIdx.x;
    const int lane = tid & 63;
    const int wid  = tid >> 6;
    const int ntile = blockIdx.x;    // 0..9
    const int a     = blockIdx.y;    // 0..39
    const int n0    = ntile * BN + wid * 32;   // this wave's column base

    const int l15 = lane & 15;
    const int lg  = lane >> 4;

    // B-frag addressing: lane holds B[k = lg*8 + j][col = n*16 + l15]
    const float* bbase = W1 + (size_t)a * C_ * C_ + (size_t)(lg * 8) * C_ + n0 + l15;
    // A-frag addressing: lane holds A[row = m*16 + l15][k = lg*8 + j]
    const short* pbase = p + (size_t)l15 * C_ + lg * 8;

    float  braw[2][16];   // [phase][n*8 + j] raw fp32 W1
    bf16x8 agr[2][4];     // [phase][m-frag]
    f32x4  acc[4][2];
    #pragma unroll
    for (int m = 0; m < 4; ++m)
        #pragma unroll
        for (int n = 0; n < 2; ++n) acc[m][n] = (f32x4){0.f, 0.f, 0.f, 0.f};

#define LOADB(KT, PH) do {                                          \
        const float* _b = bbase + (size_t)(KT) * 32 * C_;           \
        _Pragma("unroll")                                           \
        for (int j = 0; j < 8; ++j) {                               \
            braw[PH][j]     = _b[(size_t)j * C_];                   \
            braw[PH][8 + j] = _b[(size_t)j * C_ + 16];              \
        }                                                           \
    } while (0)

#define LOADA(KT, PH) do {                                          \
        const short* _p = pbase + (KT) * 32;                        \
        _Pragma("unroll")                                           \
        for (int m = 0; m < 4; ++m)                                 \
            agr[PH][m] = *reinterpret_cast<const bf16x8*>(_p + (size_t)m * 16 * C_); \
    } while (0)

    // prologue: fill both phases
    LOADB(0, 0); LOADA(0, 0);
    LOADB(1, 1); LOADA(1, 1);

    #pragma unroll
    for (int kt = 0; kt < NK; ++kt) {
        const int ph = kt & 1;           // compile-time after full unroll
        // convert current B to bf16 frags (frees braw[ph] for refill)
        bf16x8 bfrag[2];
        #pragma unroll
        for (int n = 0; n < 2; ++n)
            #pragma unroll
            for (int j = 0; j < 8; ++j)
                bfrag[n][j] = f2bf(braw[ph][n * 8 + j]);
        // prefetch kt+2 B: in flight across MFMA(kt) + all of iter kt+1
        if (kt + 2 < NK) LOADB(kt + 2, ph);
        // MFMA: 4 m-frags x 2 n-frags
        #pragma unroll
        for (int m = 0; m < 4; ++m)
            #pragma unroll
            for (int n = 0; n < 2; ++n)
                acc[m][n] = __builtin_amdgcn_mfma_f32_16x16x32_bf16(agr[ph][m], bfrag[n], acc[m][n], 0, 0, 0);
        // prefetch kt+2 A (L2-hot) after MFMAs consumed agr[ph]
        if (kt + 2 < NK) LOADA(kt + 2, ph);
    }
#undef LOADB
#undef LOADA

    // epilogue: h = hswish(acc + b1); partial = h . W2 over this wave's 32 cols
    // C/D layout: row = m*16 + lg*4 + r, col = n0 + n*16 + l15
    float b1v[2], w2v[2];
    #pragma unroll
    for (int n = 0; n < 2; ++n) {
        int col = n0 + n * 16 + l15;
        b1v[n] = b1[a * C_ + col];
        w2v[n] = W2[a * C_ + col];
    }
    float partial[4][4];
    #pragma unroll
    for (int m = 0; m < 4; ++m)
        #pragma unroll
        for (int r = 0; r < 4; ++r) {
            float s = 0.f;
            #pragma unroll
            for (int n = 0; n < 2; ++n)
                s += hswish(acc[m][n][r] + b1v[n]) * w2v[n];
            partial[m][r] = s;
        }
    // reduce across the 16 l15 lanes (stays within each 16-lane group)
    #pragma unroll
    for (int off = 8; off >= 1; off >>= 1)
        #pragma unroll
        for (int m = 0; m < 4; ++m)
            #pragma unroll
            for (int r = 0; r < 4; ++r)
                partial[m][r] += __shfl_xor(partial[m][r], off, 64);
    if (l15 == 0) {
        #pragma unroll
        for (int m = 0; m < 4; ++m)
            #pragma unroll
            for (int r = 0; r < 4; ++r)
                red[wid][m * 16 + lg * 4 + r] = partial[m][r];
    }
    __syncthreads();
    if (tid < B_) {
        float s = red[0][tid] + red[1][tid] + red[2][tid] + red[3][tid];
        part[ntile * (B_ * A_) + tid * A_ + a] = s;
    }
}

// Kernel 3: sum partials over the 10 d-tiles, add b2, sigmoid
__global__ __launch_bounds__(256) void fin_kernel(const float* __restrict__ part,
                                                  const float* __restrict__ b2,
                                                  float* __restrict__ out) {
    int idx = blockIdx.x * 256 + threadIdx.x;
    if (idx >= B_ * A_) return;
    int a = idx % A_;
    float s = b2[a];
    #pragma unroll
    for (int nb = 0; nb < NTILE; ++nb) s += part[nb * (B_ * A_) + idx];
    out[idx] = 1.0f / (1.0f + expf(-s));
}

extern "C" void kernel_launch(void* const* d_in, const int* in_sizes, int n_in,
                              void* d_out, int out_size, void* d_ws, size_t ws_size,
                              hipStream_t stream) {
    const float* x  = (const float*)d_in[0];
    const float* W1 = (const float*)d_in[1];
    const float* b1 = (const float*)d_in[2];
    const float* W2 = (const float*)d_in[3];
    const float* b2 = (const float*)d_in[4];
    float* out = (float*)d_out;

    __hip_bfloat16* p = (__hip_bfloat16*)d_ws;                      // 64*1280*2 = 160 KB
    float* part = (float*)((char*)d_ws + (size_t)B_ * C_ * 2);      // 10*64*40*4 = 100 KB

    pool_kernel<<<(B_ * C_) / POOL_ROWS, 256, 0, stream>>>(x, p);
    head_kernel<<<dim3(NTILE, A_), 256, 0, stream>>>((const short*)p, W1, b1, W2, part);
    fin_kernel<<<(B_ * A_ + 255) / 256, 256, 0, stream>>>(part, b2, out);
}

// Round 3
// 59.119 us; speedup vs baseline: 1.5772x; 1.5772x over previous
//
#include <hip/hip_runtime.h>
#include <hip/hip_bf16.h>

// Problem constants
#define B_    64
#define C_    1280
#define HW_   49
#define A_    40
#define BN    128          // d-tile per block
#define BK    64           // k-step
#define NKT   (C_/BK)      // 20
#define NTILE (C_/BN)      // 10

typedef short bf16x8 __attribute__((ext_vector_type(8)));
typedef float f32x4  __attribute__((ext_vector_type(4)));

__device__ __forceinline__ float hswish(float x) {
    float t = fminf(fmaxf(x + 3.0f, 0.0f), 6.0f);
    return x * t * (1.0f / 6.0f);
}

__device__ __forceinline__ short f2bf(float f) {
    __hip_bfloat16 h = __float2bfloat16(f);
    return __builtin_bit_cast(short, h);
}

// XOR-swizzled element index into a [rows][BK] bf16 LDS tile (row stride 128B).
// 16B-block column index XORed with row&7 -> uniform bank spread for b128 ops.
__device__ __forceinline__ int swz(int r, int k) {
    return r * BK + ((((k >> 3) ^ r) & 7) << 3) + (k & 7);
}

// Kernel 1: avg pool (7x7) + h_swish + cvt to bf16 (coalesced float4 staging)
#define POOL_ROWS 64
__global__ __launch_bounds__(256) void pool_kernel(const float* __restrict__ x,
                                                   __hip_bfloat16* __restrict__ p) {
    __shared__ float buf[POOL_ROWS * HW_];   // 3136 floats
    const int tid = threadIdx.x;
    const size_t base = (size_t)blockIdx.x * (POOL_ROWS * HW_);
    const float4* src = reinterpret_cast<const float4*>(x + base);
    #pragma unroll
    for (int i = 0; i < 3; ++i) {
        float4 v = src[tid + i * 256];
        *reinterpret_cast<float4*>(&buf[(tid + i * 256) * 4]) = v;
    }
    if (tid < 16) {
        float4 v = src[768 + tid];
        *reinterpret_cast<float4*>(&buf[(768 + tid) * 4]) = v;
    }
    __syncthreads();
    if (tid < POOL_ROWS) {
        float s = 0.f;
        #pragma unroll
        for (int j = 0; j < HW_; ++j) s += buf[tid * HW_ + j];
        s *= (1.0f / 49.0f);
        p[blockIdx.x * POOL_ROWS + tid] = __float2bfloat16(hswish(s));
    }
}

// Kernel 2: LDS-staged head GEMM, BK=64, swizzled conflict-free LDS,
// single-buffered staging regs (issue-early prefetch), 2+ blocks/CU.
__global__ __launch_bounds__(256) void head_kernel(
    const short* __restrict__ p,     // [64][1280] bf16
    const float* __restrict__ W1,    // [40][1280][1280]  ([a][k][d])
    const float* __restrict__ b1,    // [40][1280]
    const float* __restrict__ W2,    // [40][1280]
    float* __restrict__ part)        // [NTILE][64][40]
{
    __shared__ short w_lds[BN * BK];   // 16 KB, swizzled [d][k]
    __shared__ short p_lds[B_ * BK];   // 8 KB,  swizzled [b][k]

    const int tid  = threadIdx.x;
    const int lane = tid & 63;
    const int wid  = tid >> 6;
    const int ntile = blockIdx.x;      // 0..9
    const int a     = blockIdx.y;      // 0..39
    const int n0    = ntile * BN;

    const int l15 = lane & 15;
    const int lg  = lane >> 4;

    // W staging: thread owns d = tid&127, k-half (tid>>7)*32 (32 k's)
    const int sd = tid & 127;
    const int kh = (tid >> 7) * 32;
    const float* w1base = W1 + (size_t)a * C_ * C_ + n0 + sd;

    // p staging: thread owns row tid&63, k-seg (tid>>6)*16 (16 k's = 2x bf16x8)
    const int pr = tid & 63;
    const int ks = (tid >> 6) * 16;
    const short* pbase = p + (size_t)pr * C_ + ks;

    f32x4 acc[8];
    #pragma unroll
    for (int n = 0; n < 8; ++n) acc[n] = (f32x4){0.f, 0.f, 0.f, 0.f};

    float  wraw[32];
    bf16x8 praw[2];

#define LOADW(KT) do {                                              \
        const float* _wb = w1base + (size_t)((KT) * BK + kh) * C_;  \
        _Pragma("unroll")                                           \
        for (int _i = 0; _i < 32; ++_i)                             \
            wraw[_i] = _wb[(size_t)_i * C_];                        \
    } while (0)

#define LOADP(KT) do {                                              \
        const short* _pb = pbase + (KT) * BK;                       \
        praw[0] = *reinterpret_cast<const bf16x8*>(_pb);            \
        praw[1] = *reinterpret_cast<const bf16x8*>(_pb + 8);        \
    } while (0)

    LOADW(0); LOADP(0);

    for (int kt = 0; kt < NKT; ++kt) {
        __syncthreads();   // previous compute done reading LDS
        // convert + write W tile (4x ds_write_b128, conflict-free via swizzle)
        #pragma unroll
        for (int i = 0; i < 4; ++i) {
            bf16x8 v;
            #pragma unroll
            for (int j = 0; j < 8; ++j) v[j] = f2bf(wraw[i * 8 + j]);
            *reinterpret_cast<bf16x8*>(&w_lds[swz(sd, kh + i * 8)]) = v;
        }
        *reinterpret_cast<bf16x8*>(&p_lds[swz(pr, ks)])     = praw[0];
        *reinterpret_cast<bf16x8*>(&p_lds[swz(pr, ks + 8)]) = praw[1];
        __syncthreads();

        // issue-early prefetch of next k-tile (drains at next barrier = exact dep)
        if (kt + 1 < NKT) { LOADW(kt + 1); LOADP(kt + 1); }

        // compute: wave wid owns rows [wid*16, +16), all 128 cols
        #pragma unroll
        for (int h = 0; h < 2; ++h) {
            bf16x8 afrag = *reinterpret_cast<const bf16x8*>(
                &p_lds[swz(wid * 16 + l15, h * 32 + lg * 8)]);
            #pragma unroll
            for (int n = 0; n < 8; ++n) {
                bf16x8 bfrag = *reinterpret_cast<const bf16x8*>(
                    &w_lds[swz(n * 16 + l15, h * 32 + lg * 8)]);
                acc[n] = __builtin_amdgcn_mfma_f32_16x16x32_bf16(afrag, bfrag, acc[n], 0, 0, 0);
            }
        }
    }
#undef LOADW
#undef LOADP

    // epilogue: h = hswish(acc + b1); partial = h . W2 over this block's 128 cols
    // C/D layout: row = wid*16 + lg*4 + r, col = n0 + n*16 + l15
    float partial[4] = {0.f, 0.f, 0.f, 0.f};
    #pragma unroll
    for (int n = 0; n < 8; ++n) {
        int col = n0 + n * 16 + l15;
        float b1v = b1[a * C_ + col];
        float w2v = W2[a * C_ + col];
        #pragma unroll
        for (int r = 0; r < 4; ++r)
            partial[r] += hswish(acc[n][r] + b1v) * w2v;
    }
    #pragma unroll
    for (int off = 8; off >= 1; off >>= 1)
        #pragma unroll
        for (int r = 0; r < 4; ++r)
            partial[r] += __shfl_xor(partial[r], off, 64);
    if (l15 == 0) {
        int brow = wid * 16 + lg * 4;
        #pragma unroll
        for (int r = 0; r < 4; ++r)
            part[ntile * (B_ * A_) + (brow + r) * A_ + a] = partial[r];
    }
}

// Kernel 3: sum partials over the 10 d-tiles, add b2, sigmoid
__global__ __launch_bounds__(256) void fin_kernel(const float* __restrict__ part,
                                                  const float* __restrict__ b2,
                                                  float* __restrict__ out) {
    int idx = blockIdx.x * 256 + threadIdx.x;
    if (idx >= B_ * A_) return;
    int a = idx % A_;
    float s = b2[a];
    #pragma unroll
    for (int nb = 0; nb < NTILE; ++nb) s += part[nb * (B_ * A_) + idx];
    out[idx] = 1.0f / (1.0f + expf(-s));
}

extern "C" void kernel_launch(void* const* d_in, const int* in_sizes, int n_in,
                              void* d_out, int out_size, void* d_ws, size_t ws_size,
                              hipStream_t stream) {
    const float* x  = (const float*)d_in[0];
    const float* W1 = (const float*)d_in[1];
    const float* b1 = (const float*)d_in[2];
    const float* W2 = (const float*)d_in[3];
    const float* b2 = (const float*)d_in[4];
    float* out = (float*)d_out;

    __hip_bfloat16* p = (__hip_bfloat16*)d_ws;                      // 160 KB
    float* part = (float*)((char*)d_ws + (size_t)B_ * C_ * 2);      // 100 KB

    pool_kernel<<<(B_ * C_) / POOL_ROWS, 256, 0, stream>>>(x, p);
    head_kernel<<<dim3(NTILE, A_), 256, 0, stream>>>((const short*)p, W1, b1, W2, part);
    fin_kernel<<<(B_ * A_ + 255) / 256, 256, 0, stream>>>(part, b2, out);
}